// Round 14
// baseline (970.423 us; speedup 1.0000x reference)
//
#include <hip/hip_runtime.h>

// LSTM B=256, T=2048, H=128, gates 4H=512, deferred fc projection.
// R13 wall closed as: MFMA 553 (floor: 128 MFMA/CU/step) + VALU 536 + ds/bar,
// ~serialized. Tail is trans-dominated (v_exp/v_rcp ~16 cyc/wave-instr).
// This round cuts the tail:
// 1. Distributed activations: lanes 0-31 activate (i,f), 32-63 (z,o) —
//    every lane holds all 4 preacts (D rows are replicas) -> 6 trans vs 10.
// 2. Cross-half exchange via v_permlane32_swap (VALU pipe; runtime lane-id
//    probe makes it robust to either row-pairing semantic; shfl fallback).
// 3. Running accumulators + diff extraction: acc elem0 NEVER reset; tail
//    computes pre = (acc - prev) + bias + x*W_ih. Kills per-step accvgpr
//    writes; MFMA chains become pure AGPR loops (no VALU->MFMA loop-head
//    dep). fp32 drift: |acc| < ~1k -> ulp error < 1.2e-4, negligible.
//
// mfma_f32_16x16x32_f16 packing: A[q,e]=h[32kc+8q+e], B[q,e]=W_hh[row][same]
// share the HW (lane,elem)->k map -> exact. D: col=lane&15 (unit), rows all
// equal (A rows replicated) -> every lane holds its unit's 4 gate preacts.

typedef _Float16 half2v __attribute__((ext_vector_type(2)));
typedef _Float16 f16x8  __attribute__((ext_vector_type(8)));
typedef float    f32x4  __attribute__((ext_vector_type(4)));

constexpr int NB = 256;
constexpr int NT = 2048;
constexpr int NH = 128;

__device__ __forceinline__ float fexp2(float x) {
    float r;
    asm("v_exp_f32 %0, %1" : "=v"(r) : "v"(x));
    return r;
}
__device__ __forceinline__ float frcp(float x) {
    float r;
    asm("v_rcp_f32 %0, %1" : "=v"(r) : "v"(x));
    return r;
}
__device__ __forceinline__ float ftanh(float x) {  // 2/(1+2^(-2x*log2e)) - 1
    return fmaf(2.f, frcp(1.f + fexp2(x * -2.88539008f)), -1.f);
}

__device__ __forceinline__ unsigned packh2(float lo, float hi) {
    half2v p;
    p.x = (_Float16)lo;
    p.y = (_Float16)hi;
    return __builtin_bit_cast(unsigned, p);
}

__device__ __forceinline__ float dot2(unsigned int w, unsigned int h, float acc) {
    half2v a = __builtin_bit_cast(half2v, w);
    half2v b = __builtin_bit_cast(half2v, h);
#if __has_builtin(__builtin_amdgcn_fdot2)
    return __builtin_amdgcn_fdot2(a, b, acc, false);
#else
    float r;
    asm("v_dot2_f32_f16 %0, %1, %2, %3" : "=v"(r) : "v"(a), "v"(b), "v"(acc));
    return r;
#endif
}

__device__ __forceinline__ f32x4 mfma32(f16x8 a, f16x8 b, f32x4 c) {
#if __has_builtin(__builtin_amdgcn_mfma_f32_16x16x32_f16)
    return __builtin_amdgcn_mfma_f32_16x16x32_f16(a, b, c, 0, 0, 0);
#else
    asm("v_mfma_f32_16x16x32_f16 %0, %1, %2, %0" : "+v"(c) : "v"(a), "v"(b));
    return c;
#endif
}

// opposite-32-half value of x, on the VALU pipe. pick0 from the runtime
// lane-id probe (robust to either permlane32_swap row-pairing semantic).
__device__ __forceinline__ float xswap32(float x, bool pick0) {
#if __has_builtin(__builtin_amdgcn_permlane32_swap)
    unsigned xu = __builtin_bit_cast(unsigned, x);
    auto rr = __builtin_amdgcn_permlane32_swap(xu, xu, false, false);
    unsigned t2[2];
    __builtin_memcpy(t2, &rr, 8);
    return __builtin_bit_cast(float, pick0 ? t2[0] : t2[1]);
#else
    (void)pick0;
    return __shfl_xor(x, 32, 64);
#endif
}

// barrier with LDS visibility, NO vmcnt drain (fire-and-forget h stores
// stay off the 2048-iteration critical path)
__device__ __forceinline__ void barrier_lds() {
    asm volatile("s_waitcnt lgkmcnt(0)" ::: "memory");
    __builtin_amdgcn_s_barrier();
    asm volatile("" ::: "memory");
}

template <bool DEFER_FC>
__global__ __launch_bounds__(512, 2)
void lstm_k1(const float* __restrict__ x, const float* __restrict__ W_ih,
             const float* __restrict__ W_hh, const float* __restrict__ b_ih,
             const float* __restrict__ b_hh, const float* __restrict__ fc_w,
             const float* __restrict__ fc_b, float* __restrict__ out,
             _Float16* __restrict__ hws) {
    __shared__ __align__(16) float    x_lds[NT];
    __shared__ __align__(16) _Float16 h_lds[2][NH];  // double buffer
    __shared__ float red[8];                         // fallback fc partials

    const int b    = blockIdx.x;
    const int t    = threadIdx.x;   // 0..511
    const int lane = t & 63;
    const int w    = t >> 6;        // wave 0..7: units [16w, 16w+16)
    const int q    = lane >> 4;     // k-subgroup 0..3
    const int nlo  = lane & 15;     // unit-within-wave
    const int u    = 16 * w + nlo;  // this lane's hidden unit
    const int half = (lane >> 5) & 1;  // 0: activates i,f ; 1: activates z,o

    if (w < 4) __builtin_amdgcn_s_setprio(1);  // phase-shift vs co-wave

    // runtime probe: which permlane32_swap output holds the opposite half
    bool pick0 = false;
#if __has_builtin(__builtin_amdgcn_permlane32_swap)
    {
        unsigned lid = (unsigned)lane;
        auto pr = __builtin_amdgcn_permlane32_swap(lid, lid, false, false);
        unsigned p2[2];
        __builtin_memcpy(p2, &pr, 8);
        pick0 = (p2[0] != lid);
    }
#endif

    // preload x row (512 x float4)
    ((float4*)x_lds)[t] = ((const float4*)(x + (size_t)b * NT))[t];
    if (t < NH) h_lds[0][t] = (_Float16)0.f;

    // ---- persistent B-frags: 4 gate-type tiles x 4 K-chunks, f16x8 ----
    f16x8 bw[4][4];
#pragma unroll
    for (int g = 0; g < 4; ++g) {
        const float* wrow = W_hh + (size_t)(g * NH + u) * NH;
#pragma unroll
        for (int kc = 0; kc < 4; ++kc) {
            float4 f0 = *(const float4*)(wrow + kc * 32 + q * 8);
            float4 f1 = *(const float4*)(wrow + kc * 32 + q * 8 + 4);
            f16x8 v;
            v[0] = (_Float16)f0.x; v[1] = (_Float16)f0.y;
            v[2] = (_Float16)f0.z; v[3] = (_Float16)f0.w;
            v[4] = (_Float16)f1.x; v[5] = (_Float16)f1.y;
            v[6] = (_Float16)f1.z; v[7] = (_Float16)f1.w;
            bw[g][kc] = v;
        }
    }
#pragma unroll
    for (int g = 0; g < 4; ++g)
#pragma unroll
        for (int kc = 0; kc < 4; ++kc) asm volatile("" : "+v"(bw[g][kc]));

    // per-lane activation constants: this half's two gate rows
    const int g0row = (half ? 2 : 0) * NH + u;  // i or z
    const int g1row = (half ? 3 : 1) * NH + u;  // f or o
    const float bias0 = b_ih[g0row] + b_hh[g0row];
    const float bias1 = b_ih[g1row] + b_hh[g1row];
    const float wih0  = W_ih[g0row];
    const float wih1  = W_ih[g1row];
    const float kmul0 = half ? -2.88539008f : -1.44269504f;  // z uses tanh

    float c = 0.f, h = 0.f;  // cell state of unit u (consistent on all lanes)
    float prev0 = 0.f, prev1 = 0.f;  // running-acc previous values
    float fcw = 0.f, fcb = 0.f;
    if (!DEFER_FC) {
        fcw = fc_w[u];
        fcb = fc_b[0];
    }

    float*    outp = out + (size_t)b * NT;
    _Float16* hrow = DEFER_FC ? (hws + (size_t)b * NT * NH) : (_Float16*)nullptr;

    // persistent running accumulators — NEVER reset (diff extraction in tail;
    // junk elems 1-3 bounded, never read)
    f32x4 ai = {0.f, 0.f, 0.f, 0.f}, af = ai, az = ai, ao = ai;

    __syncthreads();

    for (int step = 0; step < NT; ++step) {
        // ---- A-frags: uniform broadcast reads (all 16 A rows = h) ----
        const _Float16* hbuf = h_lds[step & 1];
        float xv = x_lds[step];
        f16x8 av[4];
#pragma unroll
        for (int kc = 0; kc < 4; ++kc)
            av[kc] = *(const f16x8*)(hbuf + kc * 32 + q * 8);

        // ---- 16 MFMA: pure AGPR chains, no per-step init ----
#pragma unroll
        for (int kc = 0; kc < 4; ++kc) {
            ai = mfma32(av[kc], bw[0][kc], ai);
            af = mfma32(av[kc], bw[1][kc], af);
            az = mfma32(av[kc], bw[2][kc], az);
            ao = mfma32(av[kc], bw[3][kc], ao);
        }

        // ---- tail: diff-extract own half's two gates, activate ----
        float s_i = ai[0], s_f = af[0], s_z = az[0], s_o = ao[0];
        float d0 = half ? s_z : s_i;
        float d1 = half ? s_o : s_f;
        float pre0 = fmaf(xv, wih0, (d0 - prev0) + bias0);
        float pre1 = fmaf(xv, wih1, (d1 - prev1) + bias1);
        prev0 = d0;
        prev1 = d1;
        float r0   = frcp(1.f + fexp2(pre0 * kmul0));
        float act0 = half ? fmaf(2.f, r0, -1.f) : r0;         // i or z
        float act1 = frcp(1.f + fexp2(pre1 * -1.44269504f));  // f or o
        // cross-half exchange on the VALU pipe
        float oth0 = xswap32(act0, pick0);  // z (half0) / i (half1)
        float oth1 = xswap32(act1, pick0);  // o (half0) / f (half1)
        float gf = half ? oth1 : act1;
        float go = half ? act1 : oth1;
        // i*z is order-independent: act0*oth0 on both halves
        c = fmaf(gf, c, act0 * oth0);
        h = go * ftanh(c);

        if (lane < 16) {
            _Float16 hh = (_Float16)h;
            h_lds[(step + 1) & 1][u] = hh;
            if (DEFER_FC) hrow[(size_t)step * NH + u] = hh;  // fire-and-forget
        }
        if (!DEFER_FC) {
            float p = (lane < 16) ? h * fcw : 0.f;
#pragma unroll
            for (int m = 8; m >= 1; m >>= 1) p += __shfl_xor(p, m, 64);
            if (lane == 0) red[w] = p;
            __syncthreads();
            if (t == 0) {
                float s = red[0] + red[1] + red[2] + red[3] + red[4] + red[5] +
                          red[6] + red[7];
                outp[step] = ftanh(s + fcb);
            }
        }
        barrier_lds();  // h_lds[next] visible to all waves
    }

    // ---- final hT, cT ([1,B,H] each, after out) ----
    if (lane < 16) {
        float* hT = out + (size_t)NB * NT;
        float* cT = hT + (size_t)NB * NH;
        hT[b * NH + u] = h;
        cT[b * NH + u] = c;
    }
}

// Kernel 2: out[b,t] = tanh(dot(h[b,t,:], fc_w) + fc_b). Memory-bound.
__global__ __launch_bounds__(256) void fc_k2(const _Float16* __restrict__ hws,
                                             const float* __restrict__ fc_w,
                                             const float* __restrict__ fc_b,
                                             float* __restrict__ out) {
    __shared__ unsigned wlds[64];
    const int t = threadIdx.x;
    if (t < 64) {
        float2 f = ((const float2*)fc_w)[t];
        wlds[t] = packh2(f.x, f.y);
    }
    __syncthreads();

    const size_t idx = (size_t)blockIdx.x * 256 + t;
    const uint4* hp = (const uint4*)(hws + idx * NH);
    const uint4* wp = (const uint4*)wlds;
    float acc = 0.f;
#pragma unroll
    for (int j = 0; j < 16; ++j) {
        uint4 hv = hp[j];
        uint4 wv = wp[j];
        acc = dot2(hv.x, wv.x, acc);
        acc = dot2(hv.y, wv.y, acc);
        acc = dot2(hv.z, wv.z, acc);
        acc = dot2(hv.w, wv.w, acc);
    }
    out[idx] = ftanh(acc + fc_b[0]);
}

extern "C" void kernel_launch(void* const* d_in, const int* in_sizes, int n_in,
                              void* d_out, int out_size, void* d_ws, size_t ws_size,
                              hipStream_t stream) {
    const float* x    = (const float*)d_in[0];
    const float* W_ih = (const float*)d_in[1];
    const float* W_hh = (const float*)d_in[2];
    const float* b_ih = (const float*)d_in[3];
    const float* b_hh = (const float*)d_in[4];
    const float* fc_w = (const float*)d_in[5];
    const float* fc_b = (const float*)d_in[6];
    float* out = (float*)d_out;

    const size_t need = (size_t)NB * NT * NH * sizeof(_Float16);  // 128 MB
    if (ws_size >= need) {
        _Float16* hws = (_Float16*)d_ws;
        lstm_k1<true><<<dim3(NB), dim3(512), 0, stream>>>(
            x, W_ih, W_hh, b_ih, b_hh, fc_w, fc_b, out, hws);
        fc_k2<<<dim3(NB * NT / 256), dim3(256), 0, stream>>>(hws, fc_w, fc_b, out);
    } else {
        lstm_k1<false><<<dim3(NB), dim3(512), 0, stream>>>(
            x, W_ih, W_hh, b_ih, b_hh, fc_w, fc_b, out, nullptr);
    }
}

// Round 15
// 938.088 us; speedup vs baseline: 1.0345x; 1.0345x over previous
//
#include <hip/hip_runtime.h>

// LSTM B=256, T=2048, H=128, gates 4H=512, deferred fc projection.
// == R13 config (best: 902.8 us) + 2 zero-risk critical-path cuts ==
// R14 post-mortem: distributed-half tail + permlane32_swap REGRESSED (+80us)
// — permlane/cndmask choreography cost more than the 4 saved trans ops and
// lengthened the serial chain. Reverted.
// Wall decomposition (R13): MFMA 553 cyc (hard floor: 128 MFMA/CU/step from
// N=512 x K=128 tiling; M-waste structural at 1 batch/CU) + VALU 536 + ~70
// latency residue, ~serialized (per-step global h dependency).
// This round: (1) x_lds[step+1] prefetched BEFORE the barrier (x immutable,
// latency hides under barrier wait); (2) A-frag ds_reads issued first after
// the barrier, acc elem-0 init (uses prefetched xv only) under their shadow.
//
// mfma_f32_16x16x32_f16 packing: A[q,e]=h[32kc+8q+e], B[q,e]=W_hh[row][same]
// share the HW (lane,elem)->k map -> exact for any bijection. D: col=lane&15,
// rows replicated (all A rows = h) -> every lane's reg 0 holds gate[unit].

typedef _Float16 half2v __attribute__((ext_vector_type(2)));
typedef _Float16 f16x8  __attribute__((ext_vector_type(8)));
typedef float    f32x4  __attribute__((ext_vector_type(4)));

constexpr int NB = 256;
constexpr int NT = 2048;
constexpr int NH = 128;

__device__ __forceinline__ float fexp2(float x) {
    float r;
    asm("v_exp_f32 %0, %1" : "=v"(r) : "v"(x));
    return r;
}
__device__ __forceinline__ float frcp(float x) {
    float r;
    asm("v_rcp_f32 %0, %1" : "=v"(r) : "v"(x));
    return r;
}
__device__ __forceinline__ float fsig(float x) {   // 1/(1+2^(-x*log2e))
    return frcp(1.f + fexp2(x * -1.44269504f));
}
__device__ __forceinline__ float ftanh(float x) {  // 2/(1+2^(-2x*log2e)) - 1
    return fmaf(2.f, frcp(1.f + fexp2(x * -2.88539008f)), -1.f);
}

__device__ __forceinline__ unsigned packh2(float lo, float hi) {
    half2v p;
    p.x = (_Float16)lo;
    p.y = (_Float16)hi;
    return __builtin_bit_cast(unsigned, p);
}

__device__ __forceinline__ float dot2(unsigned int w, unsigned int h, float acc) {
    half2v a = __builtin_bit_cast(half2v, w);
    half2v b = __builtin_bit_cast(half2v, h);
#if __has_builtin(__builtin_amdgcn_fdot2)
    return __builtin_amdgcn_fdot2(a, b, acc, false);
#else
    float r;
    asm("v_dot2_f32_f16 %0, %1, %2, %3" : "=v"(r) : "v"(a), "v"(b), "v"(acc));
    return r;
#endif
}

__device__ __forceinline__ f32x4 mfma32(f16x8 a, f16x8 b, f32x4 c) {
#if __has_builtin(__builtin_amdgcn_mfma_f32_16x16x32_f16)
    return __builtin_amdgcn_mfma_f32_16x16x32_f16(a, b, c, 0, 0, 0);
#else
    asm("v_mfma_f32_16x16x32_f16 %0, %1, %2, %0" : "+v"(c) : "v"(a), "v"(b));
    return c;
#endif
}

// barrier with LDS visibility, NO vmcnt drain (fire-and-forget h stores
// stay off the 2048-iteration critical path)
__device__ __forceinline__ void barrier_lds() {
    asm volatile("s_waitcnt lgkmcnt(0)" ::: "memory");
    __builtin_amdgcn_s_barrier();
    asm volatile("" ::: "memory");
}

template <bool DEFER_FC>
__global__ __launch_bounds__(512, 2)
void lstm_k1(const float* __restrict__ x, const float* __restrict__ W_ih,
             const float* __restrict__ W_hh, const float* __restrict__ b_ih,
             const float* __restrict__ b_hh, const float* __restrict__ fc_w,
             const float* __restrict__ fc_b, float* __restrict__ out,
             _Float16* __restrict__ hws) {
    __shared__ __align__(16) float    x_lds[NT];
    __shared__ __align__(16) _Float16 h_lds[2][NH];  // double buffer
    __shared__ float red[8];                         // fallback fc partials

    const int b    = blockIdx.x;
    const int t    = threadIdx.x;   // 0..511
    const int lane = t & 63;
    const int w    = t >> 6;        // wave 0..7: units [16w, 16w+16)
    const int q    = lane >> 4;     // k-subgroup 0..3
    const int nlo  = lane & 15;     // unit-within-wave
    const int u    = 16 * w + nlo;  // this lane's hidden unit

    // phase-shift: one wave per SIMD at elevated priority so its VALU tail
    // overlaps the co-resident wave's MFMA phase
    if (w < 4) __builtin_amdgcn_s_setprio(1);

    // preload x row (512 x float4)
    ((float4*)x_lds)[t] = ((const float4*)(x + (size_t)b * NT))[t];
    if (t < NH) h_lds[0][t] = (_Float16)0.f;

    // ---- persistent B-frags: 4 gate-type tiles x 4 K-chunks, f16x8 ----
    // lane l, elem e of bw[g][kc] = W_hh[g*NH + u][32*kc + 8q + e]
    f16x8 bw[4][4];
#pragma unroll
    for (int g = 0; g < 4; ++g) {
        const float* wrow = W_hh + (size_t)(g * NH + u) * NH;
#pragma unroll
        for (int kc = 0; kc < 4; ++kc) {
            float4 f0 = *(const float4*)(wrow + kc * 32 + q * 8);
            float4 f1 = *(const float4*)(wrow + kc * 32 + q * 8 + 4);
            f16x8 v;
            v[0] = (_Float16)f0.x; v[1] = (_Float16)f0.y;
            v[2] = (_Float16)f0.z; v[3] = (_Float16)f0.w;
            v[4] = (_Float16)f1.x; v[5] = (_Float16)f1.y;
            v[6] = (_Float16)f1.z; v[7] = (_Float16)f1.w;
            bw[g][kc] = v;
        }
    }
#pragma unroll
    for (int g = 0; g < 4; ++g)
#pragma unroll
        for (int kc = 0; kc < 4; ++kc) asm volatile("" : "+v"(bw[g][kc]));

    // per-lane gate constants for unit u
    const float bi = b_ih[u] + b_hh[u];
    const float bf = b_ih[NH + u] + b_hh[NH + u];
    const float bz = b_ih[2 * NH + u] + b_hh[2 * NH + u];
    const float bo = b_ih[3 * NH + u] + b_hh[3 * NH + u];
    const float wi = W_ih[u];
    const float wf = W_ih[NH + u];
    const float wz = W_ih[2 * NH + u];
    const float wo = W_ih[3 * NH + u];

    float c = 0.f, h = 0.f;  // cell state of unit u (live on lanes < 16)
    float fcw = 0.f, fcb = 0.f;
    if (!DEFER_FC) {
        fcw = fc_w[u];
        fcb = fc_b[0];
    }

    float*    outp = out + (size_t)b * NT;
    _Float16* hrow = DEFER_FC ? (hws + (size_t)b * NT * NH) : (_Float16*)nullptr;

    // persistent accumulators: elem 0 rewritten each step; elems 1-3 NEVER
    // reset — they accumulate the (identical-row) preact sum, bounded ~6500
    // over 2048 steps, never read. Saves 20 init ops/wave/step.
    f32x4 ai = {0.f, 0.f, 0.f, 0.f}, af = ai, az = ai, ao = ai;

    __syncthreads();

    float xv = x_lds[0];  // x prefetched (immutable buffer)

    for (int step = 0; step < NT; ++step) {
        // ---- A-frag ds_reads: FIRST ops after the barrier ----
        const _Float16* hbuf = h_lds[step & 1];
        f16x8 av[4];
#pragma unroll
        for (int kc = 0; kc < 4; ++kc)
            av[kc] = *(const f16x8*)(hbuf + kc * 32 + q * 8);

        // ---- acc elem-0 init under the ds_read latency shadow ----
        // (uses only the prefetched xv — no LDS dependency)
        ai[0] = fmaf(xv, wi, bi);
        af[0] = fmaf(xv, wf, bf);
        az[0] = fmaf(xv, wz, bz);
        ao[0] = fmaf(xv, wo, bo);

        // ---- 16 MFMA: 4 gate-type chains x 4 K-chunks ----
#pragma unroll
        for (int kc = 0; kc < 4; ++kc) {
            ai = mfma32(av[kc], bw[0][kc], ai);
            af = mfma32(av[kc], bw[1][kc], af);
            az = mfma32(av[kc], bw[2][kc], az);
            ao = mfma32(av[kc], bw[3][kc], ao);
        }

        // ---- exec-masked tail: only the q=0 group does the scalar work ----
        if (lane < 16) {
            float gi = fsig(ai[0]);
            float gf = fsig(af[0]);
            float gz = ftanh(az[0]);
            float go = fsig(ao[0]);
            c = fmaf(gf, c, gi * gz);
            h = go * ftanh(c);
            _Float16 hh = (_Float16)h;
            h_lds[(step + 1) & 1][u] = hh;
            if (DEFER_FC) hrow[(size_t)step * NH + u] = hh;  // fire-and-forget
        }
        if (!DEFER_FC) {
            float p = (lane < 16) ? h * fcw : 0.f;
#pragma unroll
            for (int m = 8; m >= 1; m >>= 1) p += __shfl_xor(p, m, 64);
            if (lane == 0) red[w] = p;
            __syncthreads();
            if (t == 0) {
                float s = red[0] + red[1] + red[2] + red[3] + red[4] + red[5] +
                          red[6] + red[7];
                outp[step] = ftanh(s + fcb);
            }
        }
        // ---- prefetch next x BEFORE the barrier: its LDS latency completes
        // during the barrier wait instead of after it ----
        xv = x_lds[(step + 1) & (NT - 1)];
        barrier_lds();  // h_lds[next] visible to all waves
    }

    // ---- final hT, cT ([1,B,H] each, after out) ----
    if (lane < 16) {
        float* hT = out + (size_t)NB * NT;
        float* cT = hT + (size_t)NB * NH;
        hT[b * NH + u] = h;
        cT[b * NH + u] = c;
    }
}

// Kernel 2: out[b,t] = tanh(dot(h[b,t,:], fc_w) + fc_b). Memory-bound.
__global__ __launch_bounds__(256) void fc_k2(const _Float16* __restrict__ hws,
                                             const float* __restrict__ fc_w,
                                             const float* __restrict__ fc_b,
                                             float* __restrict__ out) {
    __shared__ unsigned wlds[64];
    const int t = threadIdx.x;
    if (t < 64) {
        float2 f = ((const float2*)fc_w)[t];
        wlds[t] = packh2(f.x, f.y);
    }
    __syncthreads();

    const size_t idx = (size_t)blockIdx.x * 256 + t;
    const uint4* hp = (const uint4*)(hws + idx * NH);
    const uint4* wp = (const uint4*)wlds;
    float acc = 0.f;
#pragma unroll
    for (int j = 0; j < 16; ++j) {
        uint4 hv = hp[j];
        uint4 wv = wp[j];
        acc = dot2(hv.x, wv.x, acc);
        acc = dot2(hv.y, wv.y, acc);
        acc = dot2(hv.z, wv.z, acc);
        acc = dot2(hv.w, wv.w, acc);
    }
    out[idx] = ftanh(acc + fc_b[0]);
}

extern "C" void kernel_launch(void* const* d_in, const int* in_sizes, int n_in,
                              void* d_out, int out_size, void* d_ws, size_t ws_size,
                              hipStream_t stream) {
    const float* x    = (const float*)d_in[0];
    const float* W_ih = (const float*)d_in[1];
    const float* W_hh = (const float*)d_in[2];
    const float* b_ih = (const float*)d_in[3];
    const float* b_hh = (const float*)d_in[4];
    const float* fc_w = (const float*)d_in[5];
    const float* fc_b = (const float*)d_in[6];
    float* out = (float*)d_out;

    const size_t need = (size_t)NB * NT * NH * sizeof(_Float16);  // 128 MB
    if (ws_size >= need) {
        _Float16* hws = (_Float16*)d_ws;
        lstm_k1<true><<<dim3(NB), dim3(512), 0, stream>>>(
            x, W_ih, W_hh, b_ih, b_hh, fc_w, fc_b, out, hws);
        fc_k2<<<dim3(NB * NT / 256), dim3(256), 0, stream>>>(hws, fc_w, fc_b, out);
    } else {
        lstm_k1<false><<<dim3(NB), dim3(512), 0, stream>>>(
            x, W_ih, W_hh, b_ih, b_hh, fc_w, fc_b, out, nullptr);
    }
}

// Round 16
// 901.284 us; speedup vs baseline: 1.0767x; 1.0408x over previous
//
#include <hip/hip_runtime.h>

// LSTM B=256, T=2048, H=128, gates 4H=512, deferred fc projection.
// == EXACT revert to the best configuration (round-12 submission, measured
// 902.85 us total / ~985 us k1). R14 (tail redistribution) and R15
// (prefetch/reorder) both regressed ~3-8%; this body's compiler schedule is
// the best found. ==
// Wall decomposition: MFMA ~553 cyc/step (hard floor: 128 MFMA/CU/step from
// N=512 x K=128 / 16x32 tiling; M=1/16 waste structural at 1 batch/CU) +
// VALU ~536 cyc (trans-dominated tail, dependency-chained) + ~70 residue.
// Combined pipe busy ~92% of wall; serialization is data-dependency-forced.
//
// mfma_f32_16x16x32_f16 packing: A[q,e]=h[32kc+8q+e], B[q,e]=W_hh[row][same]
// share the HW (lane,elem)->k map -> exact for any bijection. D: col=lane&15,
// rows replicated (all A rows = h) -> every lane's reg 0 holds gate[unit].

typedef _Float16 half2v __attribute__((ext_vector_type(2)));
typedef _Float16 f16x8  __attribute__((ext_vector_type(8)));
typedef float    f32x4  __attribute__((ext_vector_type(4)));

constexpr int NB = 256;
constexpr int NT = 2048;
constexpr int NH = 128;

__device__ __forceinline__ float fexp2(float x) {
    float r;
    asm("v_exp_f32 %0, %1" : "=v"(r) : "v"(x));
    return r;
}
__device__ __forceinline__ float frcp(float x) {
    float r;
    asm("v_rcp_f32 %0, %1" : "=v"(r) : "v"(x));
    return r;
}
__device__ __forceinline__ float fsig(float x) {   // 1/(1+2^(-x*log2e))
    return frcp(1.f + fexp2(x * -1.44269504f));
}
__device__ __forceinline__ float ftanh(float x) {  // 2/(1+2^(-2x*log2e)) - 1
    return fmaf(2.f, frcp(1.f + fexp2(x * -2.88539008f)), -1.f);
}

__device__ __forceinline__ unsigned packh2(float lo, float hi) {
    half2v p;
    p.x = (_Float16)lo;
    p.y = (_Float16)hi;
    return __builtin_bit_cast(unsigned, p);
}

__device__ __forceinline__ float dot2(unsigned int w, unsigned int h, float acc) {
    half2v a = __builtin_bit_cast(half2v, w);
    half2v b = __builtin_bit_cast(half2v, h);
#if __has_builtin(__builtin_amdgcn_fdot2)
    return __builtin_amdgcn_fdot2(a, b, acc, false);
#else
    float r;
    asm("v_dot2_f32_f16 %0, %1, %2, %3" : "=v"(r) : "v"(a), "v"(b), "v"(acc));
    return r;
#endif
}

__device__ __forceinline__ f32x4 mfma32(f16x8 a, f16x8 b, f32x4 c) {
#if __has_builtin(__builtin_amdgcn_mfma_f32_16x16x32_f16)
    return __builtin_amdgcn_mfma_f32_16x16x32_f16(a, b, c, 0, 0, 0);
#else
    asm("v_mfma_f32_16x16x32_f16 %0, %1, %2, %0" : "+v"(c) : "v"(a), "v"(b));
    return c;
#endif
}

// barrier with LDS visibility, NO vmcnt drain (fire-and-forget h stores
// stay off the 2048-iteration critical path)
__device__ __forceinline__ void barrier_lds() {
    asm volatile("s_waitcnt lgkmcnt(0)" ::: "memory");
    __builtin_amdgcn_s_barrier();
    asm volatile("" ::: "memory");
}

template <bool DEFER_FC>
__global__ __launch_bounds__(512, 2)
void lstm_k1(const float* __restrict__ x, const float* __restrict__ W_ih,
             const float* __restrict__ W_hh, const float* __restrict__ b_ih,
             const float* __restrict__ b_hh, const float* __restrict__ fc_w,
             const float* __restrict__ fc_b, float* __restrict__ out,
             _Float16* __restrict__ hws) {
    __shared__ __align__(16) float    x_lds[NT];
    __shared__ __align__(16) _Float16 h_lds[2][NH];  // double buffer
    __shared__ float red[8];                         // fallback fc partials

    const int b    = blockIdx.x;
    const int t    = threadIdx.x;   // 0..511
    const int lane = t & 63;
    const int w    = t >> 6;        // wave 0..7: units [16w, 16w+16)
    const int q    = lane >> 4;     // k-subgroup 0..3
    const int nlo  = lane & 15;     // unit-within-wave
    const int u    = 16 * w + nlo;  // this lane's hidden unit

    // phase-shift: one wave per SIMD runs at elevated priority so its VALU
    // tail overlaps the co-resident wave's MFMA phase
    if (w < 4) __builtin_amdgcn_s_setprio(1);

    // preload x row (512 x float4)
    ((float4*)x_lds)[t] = ((const float4*)(x + (size_t)b * NT))[t];
    if (t < NH) h_lds[0][t] = (_Float16)0.f;

    // ---- persistent B-frags: 4 gate-type tiles x 4 K-chunks, f16x8 ----
    // lane l, elem e of bw[g][kc] = W_hh[g*NH + u][32*kc + 8q + e]
    f16x8 bw[4][4];
#pragma unroll
    for (int g = 0; g < 4; ++g) {
        const float* wrow = W_hh + (size_t)(g * NH + u) * NH;
#pragma unroll
        for (int kc = 0; kc < 4; ++kc) {
            float4 f0 = *(const float4*)(wrow + kc * 32 + q * 8);
            float4 f1 = *(const float4*)(wrow + kc * 32 + q * 8 + 4);
            f16x8 v;
            v[0] = (_Float16)f0.x; v[1] = (_Float16)f0.y;
            v[2] = (_Float16)f0.z; v[3] = (_Float16)f0.w;
            v[4] = (_Float16)f1.x; v[5] = (_Float16)f1.y;
            v[6] = (_Float16)f1.z; v[7] = (_Float16)f1.w;
            bw[g][kc] = v;
        }
    }
#pragma unroll
    for (int g = 0; g < 4; ++g)
#pragma unroll
        for (int kc = 0; kc < 4; ++kc) asm volatile("" : "+v"(bw[g][kc]));

    // per-lane gate constants for unit u
    const float bi = b_ih[u] + b_hh[u];
    const float bf = b_ih[NH + u] + b_hh[NH + u];
    const float bz = b_ih[2 * NH + u] + b_hh[2 * NH + u];
    const float bo = b_ih[3 * NH + u] + b_hh[3 * NH + u];
    const float wi = W_ih[u];
    const float wf = W_ih[NH + u];
    const float wz = W_ih[2 * NH + u];
    const float wo = W_ih[3 * NH + u];

    float c = 0.f, h = 0.f;  // cell state of unit u (live on lanes < 16)
    float fcw = 0.f, fcb = 0.f;
    if (!DEFER_FC) {
        fcw = fc_w[u];
        fcb = fc_b[0];
    }

    float*    outp = out + (size_t)b * NT;
    _Float16* hrow = DEFER_FC ? (hws + (size_t)b * NT * NH) : (_Float16*)nullptr;

    // persistent accumulators: elem 0 rewritten each step; elems 1-3 NEVER
    // reset — they accumulate the (identical-row) preact sum, bounded ~6500
    // over 2048 steps, never read. Saves 20 init ops/wave/step.
    f32x4 ai = {0.f, 0.f, 0.f, 0.f}, af = ai, az = ai, ao = ai;

    __syncthreads();

    for (int step = 0; step < NT; ++step) {
        // ---- A-frags: uniform broadcast reads (all 16 A rows = h) ----
        const _Float16* hbuf = h_lds[step & 1];
        float xv = x_lds[step];
        f16x8 av[4];
#pragma unroll
        for (int kc = 0; kc < 4; ++kc)
            av[kc] = *(const f16x8*)(hbuf + kc * 32 + q * 8);

        // ---- acc elem-0 init: bias + x*W_ih folded, 4 fma only ----
        ai[0] = fmaf(xv, wi, bi);
        af[0] = fmaf(xv, wf, bf);
        az[0] = fmaf(xv, wz, bz);
        ao[0] = fmaf(xv, wo, bo);

        // ---- 16 MFMA: 4 gate-type chains x 4 K-chunks ----
#pragma unroll
        for (int kc = 0; kc < 4; ++kc) {
            ai = mfma32(av[kc], bw[0][kc], ai);
            af = mfma32(av[kc], bw[1][kc], af);
            az = mfma32(av[kc], bw[2][kc], az);
            ao = mfma32(av[kc], bw[3][kc], ao);
        }

        // ---- exec-masked tail: only the q=0 group does the scalar work ----
        if (lane < 16) {
            float gi = fsig(ai[0]);
            float gf = fsig(af[0]);
            float gz = ftanh(az[0]);
            float go = fsig(ao[0]);
            c = fmaf(gf, c, gi * gz);
            h = go * ftanh(c);
            _Float16 hh = (_Float16)h;
            h_lds[(step + 1) & 1][u] = hh;
            if (DEFER_FC) hrow[(size_t)step * NH + u] = hh;  // fire-and-forget
        }
        if (!DEFER_FC) {
            float p = (lane < 16) ? h * fcw : 0.f;
#pragma unroll
            for (int m = 8; m >= 1; m >>= 1) p += __shfl_xor(p, m, 64);
            if (lane == 0) red[w] = p;
            __syncthreads();
            if (t == 0) {
                float s = red[0] + red[1] + red[2] + red[3] + red[4] + red[5] +
                          red[6] + red[7];
                outp[step] = ftanh(s + fcb);
            }
        }
        barrier_lds();  // h_lds[next] visible to all waves
    }

    // ---- final hT, cT ([1,B,H] each, after out) ----
    if (lane < 16) {
        float* hT = out + (size_t)NB * NT;
        float* cT = hT + (size_t)NB * NH;
        hT[b * NH + u] = h;
        cT[b * NH + u] = c;
    }
}

// Kernel 2: out[b,t] = tanh(dot(h[b,t,:], fc_w) + fc_b). Memory-bound.
__global__ __launch_bounds__(256) void fc_k2(const _Float16* __restrict__ hws,
                                             const float* __restrict__ fc_w,
                                             const float* __restrict__ fc_b,
                                             float* __restrict__ out) {
    __shared__ unsigned wlds[64];
    const int t = threadIdx.x;
    if (t < 64) {
        float2 f = ((const float2*)fc_w)[t];
        wlds[t] = packh2(f.x, f.y);
    }
    __syncthreads();

    const size_t idx = (size_t)blockIdx.x * 256 + t;
    const uint4* hp = (const uint4*)(hws + idx * NH);
    const uint4* wp = (const uint4*)wlds;
    float acc = 0.f;
#pragma unroll
    for (int j = 0; j < 16; ++j) {
        uint4 hv = hp[j];
        uint4 wv = wp[j];
        acc = dot2(hv.x, wv.x, acc);
        acc = dot2(hv.y, wv.y, acc);
        acc = dot2(hv.z, wv.z, acc);
        acc = dot2(hv.w, wv.w, acc);
    }
    out[idx] = ftanh(acc + fc_b[0]);
}

extern "C" void kernel_launch(void* const* d_in, const int* in_sizes, int n_in,
                              void* d_out, int out_size, void* d_ws, size_t ws_size,
                              hipStream_t stream) {
    const float* x    = (const float*)d_in[0];
    const float* W_ih = (const float*)d_in[1];
    const float* W_hh = (const float*)d_in[2];
    const float* b_ih = (const float*)d_in[3];
    const float* b_hh = (const float*)d_in[4];
    const float* fc_w = (const float*)d_in[5];
    const float* fc_b = (const float*)d_in[6];
    float* out = (float*)d_out;

    const size_t need = (size_t)NB * NT * NH * sizeof(_Float16);  // 128 MB
    if (ws_size >= need) {
        _Float16* hws = (_Float16*)d_ws;
        lstm_k1<true><<<dim3(NB), dim3(512), 0, stream>>>(
            x, W_ih, W_hh, b_ih, b_hh, fc_w, fc_b, out, hws);
        fc_k2<<<dim3(NB * NT / 256), dim3(256), 0, stream>>>(hws, fc_w, fc_b, out);
    } else {
        lstm_k1<false><<<dim3(NB), dim3(512), 0, stream>>>(
            x, W_ih, W_hh, b_ih, b_hh, fc_w, fc_b, out, nullptr);
    }
}